// Round 2
// baseline (304.408 us; speedup 1.0000x reference)
//
#include <hip/hip_runtime.h>
#include <cstdint>
#include <cstddef>

// ---------------------------------------------------------------------------
// CrossAttention: out = softmax((x Wq)(ctx Wk)^T / sqrt(64)) (ctx Wv) Wo + bo
// B=4, N=M=2048, QD=1024, CD=768, H=8, DH=64, INNER=512
// bf16 MFMA pipeline, fp32 accumulation everywhere.
// ---------------------------------------------------------------------------

typedef __bf16 bf16;
typedef __bf16 bf16x8 __attribute__((ext_vector_type(8)));
typedef __bf16 bf16x4 __attribute__((ext_vector_type(4)));
typedef float  f32x4  __attribute__((ext_vector_type(4)));

#define B_     4
#define N_     2048
#define M_     2048
#define QD_    1024
#define CD_    768
#define H_     8
#define DH_    64
#define INNER_ 512

__device__ __forceinline__ void gload_lds16(const void* g, void* l) {
  // 16B direct global->LDS. LDS dest is wave-uniform base + lane*16.
  __builtin_amdgcn_global_load_lds(
      (__attribute__((address_space(1))) unsigned int*)g,
      (__attribute__((address_space(3))) unsigned int*)l, 16, 0, 0);
}

// ---------------- fp32 -> bf16 elementwise (4 elems/thread) ----------------
__global__ __launch_bounds__(256) void k_cvt(const float* __restrict__ in,
                                             bf16* __restrict__ out) {
  int i = blockIdx.x * 256 + threadIdx.x;
  float4 v = reinterpret_cast<const float4*>(in)[i];
  bf16x4 o;
  o[0] = (bf16)v.x; o[1] = (bf16)v.y; o[2] = (bf16)v.z; o[3] = (bf16)v.w;
  reinterpret_cast<bf16x4*>(out)[i] = o;
}

// -------- weight transpose+convert: in[K][N] fp32 -> out[N][K] bf16 --------
__global__ __launch_bounds__(256) void k_wT(const float* __restrict__ in,
                                            bf16* __restrict__ out, int K, int N) {
  int t = blockIdx.x * 256 + threadIdx.x;   // over N*K, write-coalesced
  int n = t / K, k = t - n * K;
  out[t] = (bf16)in[(size_t)k * N + n];
}

// ---- V transpose: V[b][m][h*64+d] -> VT[((b*8+h)*64+d)][m]  (bf16) --------
__global__ __launch_bounds__(256) void k_vT(const bf16* __restrict__ V,
                                            bf16* __restrict__ VT) {
  int t = blockIdx.x * 256 + threadIdx.x;   // over B*H*DH*M, write-coalesced
  int m = t & (M_ - 1);
  int rest = t >> 11;          // (b*8+h)*64 + d
  int d = rest & 63;
  int bh = rest >> 6;          // b*8+h
  VT[t] = V[((size_t)((bh >> 3) * M_ + m)) * INNER_ + (bh & 7) * DH_ + d];
}

// ---------------------------------------------------------------------------
// GEMM  C[M x N] = A[M x K] @ BT[N x K]^T   (bf16 in, fp32 acc)
// 128x128 tile, BK=32, 4 waves (each 64x64 = 4x4 frags of 16x16x32 MFMA).
// LDS tiles [128 rows][32 cols] bf16 (64B rows, 4x16B slots), XOR-swizzled:
// physical slot = logical slot ^ ((row>>1)&3)  -- involution, applied both to
// the global source of global_load_lds and to the ds_read address.
// ---------------------------------------------------------------------------
__device__ __forceinline__ void gemm_core(
    const bf16* __restrict__ A, const bf16* __restrict__ BT,
    bf16* __restrict__ Cb, float* __restrict__ Cf, const float* __restrict__ bias,
    int Kdim, int Ndim, float alpha) {
  __shared__ char lds[16384];          // A: [0,8192)  B: [8192,16384)
  const int t = threadIdx.x;
  const int wid = t >> 6, l = t & 63, g = l >> 4, r16 = l & 15;
  const int wr = wid >> 1, wc = wid & 1;
  const int m0 = blockIdx.x * 128, n0 = blockIdx.y * 128;

  f32x4 acc[4][4];
#pragma unroll
  for (int ai = 0; ai < 4; ++ai)
#pragma unroll
    for (int bj = 0; bj < 4; ++bj) acc[ai][bj] = (f32x4){0.f, 0.f, 0.f, 0.f};

  // staging addressing: 256 thr * 16B = 4KB = 64 rows/issue, 4 slots per row
  const int rS = t >> 2;                        // row within issue (0..63)
  const int lsS = (t & 3) ^ ((rS >> 1) & 3);    // logical slot (involution)
  const size_t a0 = (size_t)(m0 + rS) * Kdim + lsS * 8;
  const size_t a1 = (size_t)(m0 + 64 + rS) * Kdim + lsS * 8;
  const size_t b0 = (size_t)(n0 + rS) * Kdim + lsS * 8;
  const size_t b1 = (size_t)(n0 + 64 + rS) * Kdim + lsS * 8;
  char* ldsA = lds;
  char* ldsB = lds + 8192;

  for (int k0 = 0; k0 < Kdim; k0 += 32) {
    __syncthreads();                    // prev compute done before overwrite
    gload_lds16(A + a0 + k0, ldsA + wid * 1024);
    gload_lds16(A + a1 + k0, ldsA + 4096 + wid * 1024);
    gload_lds16(BT + b0 + k0, ldsB + wid * 1024);
    gload_lds16(BT + b1 + k0, ldsB + 4096 + wid * 1024);
    __syncthreads();                    // drains vmcnt before reads

    bf16x8 af[4], bfr[4];
#pragma unroll
    for (int i = 0; i < 4; ++i) {
      const int rowA = wr * 64 + i * 16 + r16;
      af[i] = *reinterpret_cast<const bf16x8*>(
          ldsA + rowA * 64 + ((g ^ ((rowA >> 1) & 3)) << 4));
      const int rowB = wc * 64 + i * 16 + r16;
      bfr[i] = *reinterpret_cast<const bf16x8*>(
          ldsB + rowB * 64 + ((g ^ ((rowB >> 1) & 3)) << 4));
    }
#pragma unroll
    for (int ai = 0; ai < 4; ++ai)
#pragma unroll
      for (int bj = 0; bj < 4; ++bj)
        acc[ai][bj] = __builtin_amdgcn_mfma_f32_16x16x32_bf16(
            af[ai], bfr[bj], acc[ai][bj], 0, 0, 0);
  }

  // epilogue: C/D layout col = lane&15, row = (lane>>4)*4 + reg  [m89]
#pragma unroll
  for (int ai = 0; ai < 4; ++ai)
#pragma unroll
    for (int bj = 0; bj < 4; ++bj)
#pragma unroll
      for (int r = 0; r < 4; ++r) {
        const int row = m0 + wr * 64 + ai * 16 + g * 4 + r;
        const int col = n0 + wc * 64 + bj * 16 + r16;
        const float v = acc[ai][bj][r] * alpha;
        if (Cf) Cf[(size_t)row * Ndim + col] = v + bias[col];
        else    Cb[(size_t)row * Ndim + col] = (bf16)v;
      }
}

// fused QKV projection: z=0 -> Q (K=1024, alpha=1/8), z=1 -> K, z=2 -> V
__global__ __launch_bounds__(256) void k_gemm_qkv(
    const bf16* __restrict__ xb, const bf16* __restrict__ cb,
    const bf16* __restrict__ WqT, const bf16* __restrict__ WkT,
    const bf16* __restrict__ WvT,
    bf16* __restrict__ Q, bf16* __restrict__ K, bf16* __restrict__ V) {
  const int z = blockIdx.z;
  gemm_core(z == 0 ? xb : cb,
            z == 0 ? WqT : (z == 1 ? WkT : WvT),
            z == 0 ? Q : (z == 1 ? K : V),
            nullptr, nullptr,
            z == 0 ? QD_ : CD_, INNER_,
            z == 0 ? 0.125f : 1.0f);
}

__global__ __launch_bounds__(256) void k_gemm_out(
    const bf16* __restrict__ AO, const bf16* __restrict__ WoT,
    float* __restrict__ Cout, const float* __restrict__ bias) {
  gemm_core(AO, WoT, nullptr, Cout, bias, INNER_, QD_, 1.0f);
}

// ---------------------------------------------------------------------------
// Flash attention: block = (64 q-rows, one (b,h)); 4 waves x 16 q-rows.
// K tile [64 kj][64 d] and VT tile [64 d][64 kj] in LDS (128B rows, 8x16B
// slots, swizzle: physical slot = logical ^ (row&7)).  Online softmax.
// P goes through padded per-wave LDS ([16][72] bf16) to reach A-frag layout.
// ---------------------------------------------------------------------------
__global__ __launch_bounds__(256) void k_attn(const bf16* __restrict__ Qg,
                                              const bf16* __restrict__ Kg,
                                              const bf16* __restrict__ VTg,
                                              bf16* __restrict__ AO) {
  __shared__ char lds[25600];  // K:[0,8192) VT:[8192,16384) P:16384+w*2304
  const int t = threadIdx.x;
  const int w = t >> 6, l = t & 63, g = l >> 4, r16 = l & 15;
  const int qt = blockIdx.x, h = blockIdx.y, b = blockIdx.z;
  const int q0 = qt * 64;

  // Q fragments in registers (scale already folded into Q by the QKV GEMM)
  const bf16* qptr =
      Qg + ((size_t)(b * N_ + q0 + w * 16 + r16)) * INNER_ + h * DH_ + g * 8;
  const bf16x8 qf0 = *reinterpret_cast<const bf16x8*>(qptr);
  const bf16x8 qf1 = *reinterpret_cast<const bf16x8*>(qptr + 32);

  f32x4 acc[4];
  float m_run[4], l_run[4];
#pragma unroll
  for (int i = 0; i < 4; ++i) {
    acc[i] = (f32x4){0.f, 0.f, 0.f, 0.f};
    m_run[i] = -1e30f;
    l_run[i] = 0.f;
  }

  char* Pb = lds + 16384 + w * 2304;            // [16][72] bf16, 144B rows
  const int rstg = t >> 3;                      // 0..31 row within issue
  const int lstg = (t & 7) ^ (rstg & 7);        // logical slot (involution)
  const size_t kbase = (size_t)(b * M_) * INNER_ + h * DH_;
  const size_t vbase = (size_t)((b * H_ + h) * DH_) * (size_t)M_;
  char* dK0 = lds + w * 1024;
  char* dK1 = lds + 4096 + w * 1024;
  char* dV0 = lds + 8192 + w * 1024;
  char* dV1 = lds + 8192 + 4096 + w * 1024;

  for (int mt = 0; mt < M_ / 64; ++mt) {
    const int m0 = mt * 64;
    __syncthreads();   // everyone done reading previous K/VT tiles
    gload_lds16(Kg + kbase + (size_t)(m0 + rstg) * INNER_ + lstg * 8, dK0);
    gload_lds16(Kg + kbase + (size_t)(m0 + 32 + rstg) * INNER_ + lstg * 8, dK1);
    gload_lds16(VTg + vbase + (size_t)rstg * M_ + m0 + lstg * 8, dV0);
    gload_lds16(VTg + vbase + (size_t)(32 + rstg) * M_ + m0 + lstg * 8, dV1);
    __syncthreads();   // drains vmcnt(0): tiles resident

    // ---- S = Q K^T for this wave's 16 q-rows x 64 kj ----
    f32x4 s[4];
#pragma unroll
    for (int nf = 0; nf < 4; ++nf) {
      s[nf] = (f32x4){0.f, 0.f, 0.f, 0.f};
      const int row = nf * 16 + r16;  // kj-local
      const bf16x8 kb0 = *reinterpret_cast<const bf16x8*>(
          lds + row * 128 + ((g ^ (row & 7)) << 4));
      const bf16x8 kb1 = *reinterpret_cast<const bf16x8*>(
          lds + row * 128 + (((4 + g) ^ (row & 7)) << 4));
      s[nf] = __builtin_amdgcn_mfma_f32_16x16x32_bf16(qf0, kb0, s[nf], 0, 0, 0);
      s[nf] = __builtin_amdgcn_mfma_f32_16x16x32_bf16(qf1, kb1, s[nf], 0, 0, 0);
    }

    // ---- online softmax (row = g*4 + reg, reduce over 16-lane group) ----
    float mnew[4], corr[4], rsum[4];
#pragma unroll
    for (int r = 0; r < 4; ++r) {
      float mx = fmaxf(fmaxf(s[0][r], s[1][r]), fmaxf(s[2][r], s[3][r]));
      mx = fmaxf(mx, __shfl_xor(mx, 1, 64));
      mx = fmaxf(mx, __shfl_xor(mx, 2, 64));
      mx = fmaxf(mx, __shfl_xor(mx, 4, 64));
      mx = fmaxf(mx, __shfl_xor(mx, 8, 64));
      mnew[r] = fmaxf(m_run[r], mx);
      corr[r] = __expf(m_run[r] - mnew[r]);
      m_run[r] = mnew[r];
      rsum[r] = 0.f;
    }
#pragma unroll
    for (int nf = 0; nf < 4; ++nf)
#pragma unroll
      for (int r = 0; r < 4; ++r) {
        const float p = __expf(s[nf][r] - mnew[r]);
        rsum[r] += p;
        *reinterpret_cast<bf16*>(Pb + (g * 4 + r) * 144 + (nf * 16 + r16) * 2) =
            (bf16)p;
      }
#pragma unroll
    for (int r = 0; r < 4; ++r) {
      float rs = rsum[r];
      rs += __shfl_xor(rs, 1, 64);
      rs += __shfl_xor(rs, 2, 64);
      rs += __shfl_xor(rs, 4, 64);
      rs += __shfl_xor(rs, 8, 64);
      l_run[r] = l_run[r] * corr[r] + rs;
    }
#pragma unroll
    for (int nf = 0; nf < 4; ++nf)
#pragma unroll
      for (int r = 0; r < 4; ++r) acc[nf][r] *= corr[r];

    // ---- O += P V  (A-frag from P_lds, B-frag from VT_lds) ----
#pragma unroll
    for (int ks = 0; ks < 2; ++ks) {
      const bf16x8 pa = *reinterpret_cast<const bf16x8*>(
          Pb + r16 * 144 + ks * 64 + g * 16);
#pragma unroll
      for (int nf = 0; nf < 4; ++nf) {
        const int row = nf * 16 + r16;  // d-local
        const bf16x8 vb = *reinterpret_cast<const bf16x8*>(
            lds + 8192 + row * 128 + (((ks * 4 + g) ^ (row & 7)) << 4));
        acc[nf] = __builtin_amdgcn_mfma_f32_16x16x32_bf16(pa, vb, acc[nf], 0, 0, 0);
      }
    }
  }

  // ---- normalize + store ----
#pragma unroll
  for (int nf = 0; nf < 4; ++nf)
#pragma unroll
    for (int r = 0; r < 4; ++r) {
      const size_t idx = ((size_t)(b * N_ + q0 + w * 16 + g * 4 + r)) * INNER_ +
                         h * DH_ + nf * 16 + r16;
      AO[idx] = (bf16)(acc[nf][r] / l_run[r]);
    }
}

// ---------------------------------------------------------------------------
extern "C" void kernel_launch(void* const* d_in, const int* in_sizes, int n_in,
                              void* d_out, int out_size, void* d_ws, size_t ws_size,
                              hipStream_t stream) {
  const float* x   = (const float*)d_in[0];
  const float* ctx = (const float*)d_in[1];
  const float* Wq  = (const float*)d_in[2];
  const float* Wk  = (const float*)d_in[3];
  const float* Wv  = (const float*)d_in[4];
  const float* Wo  = (const float*)d_in[5];
  const float* bo  = (const float*)d_in[6];
  float* out = (float*)d_out;

  char* ws = (char*)d_ws;
  bf16* xb  = (bf16*)ws; ws += (size_t)B_ * N_ * QD_ * 2;
  bf16* cb  = (bf16*)ws; ws += (size_t)B_ * M_ * CD_ * 2;
  bf16* WqT = (bf16*)ws; ws += (size_t)QD_ * INNER_ * 2;
  bf16* WkT = (bf16*)ws; ws += (size_t)CD_ * INNER_ * 2;
  bf16* WvT = (bf16*)ws; ws += (size_t)CD_ * INNER_ * 2;
  bf16* WoT = (bf16*)ws; ws += (size_t)INNER_ * QD_ * 2;
  bf16* Qb  = (bf16*)ws; ws += (size_t)B_ * N_ * INNER_ * 2;
  bf16* Kb  = (bf16*)ws; ws += (size_t)B_ * M_ * INNER_ * 2;
  bf16* Vb  = (bf16*)ws; ws += (size_t)B_ * M_ * INNER_ * 2;
  bf16* VTb = (bf16*)ws; ws += (size_t)B_ * M_ * INNER_ * 2;
  bf16* AOb = (bf16*)ws; ws += (size_t)B_ * N_ * INNER_ * 2;

  k_cvt<<<(B_ * N_ * QD_) / 1024, 256, 0, stream>>>(x, xb);
  k_cvt<<<(B_ * M_ * CD_) / 1024, 256, 0, stream>>>(ctx, cb);
  k_wT<<<(QD_ * INNER_) / 256, 256, 0, stream>>>(Wq, WqT, QD_, INNER_);
  k_wT<<<(CD_ * INNER_) / 256, 256, 0, stream>>>(Wk, WkT, CD_, INNER_);
  k_wT<<<(CD_ * INNER_) / 256, 256, 0, stream>>>(Wv, WvT, CD_, INNER_);
  k_wT<<<(INNER_ * QD_) / 256, 256, 0, stream>>>(Wo, WoT, INNER_, QD_);

  k_gemm_qkv<<<dim3(64, 4, 3), 256, 0, stream>>>(xb, cb, WqT, WkT, WvT,
                                                 Qb, Kb, Vb);
  k_vT<<<(B_ * H_ * DH_ * M_) / 256, 256, 0, stream>>>(Vb, VTb);
  k_attn<<<dim3(N_ / 64, H_, B_), 256, 0, stream>>>(Qb, Kb, VTb, AOb);
  k_gemm_out<<<dim3(64, 8), 256, 0, stream>>>(AOb, WoT, out, bo);
}

// Round 3
// 251.307 us; speedup vs baseline: 1.2113x; 1.2113x over previous
//
#include <hip/hip_runtime.h>
#include <cstdint>
#include <cstddef>

// ---------------------------------------------------------------------------
// CrossAttention: out = softmax((x Wq)(ctx Wk)^T / sqrt(64)) (ctx Wv) Wo + bo
// B=4, N=M=2048, QD=1024, CD=768, H=8, DH=64, INNER=512
// bf16 MFMA pipeline, fp32 accumulation everywhere.
// ---------------------------------------------------------------------------

typedef __bf16 bf16;
typedef __bf16 bf16x8 __attribute__((ext_vector_type(8)));
typedef __bf16 bf16x4 __attribute__((ext_vector_type(4)));
typedef float  f32x4  __attribute__((ext_vector_type(4)));
typedef float  f32x16 __attribute__((ext_vector_type(16)));

#define B_     4
#define N_     2048
#define M_     2048
#define QD_    1024
#define CD_    768
#define H_     8
#define DH_    64
#define INNER_ 512

__device__ __forceinline__ void gload_lds16(const void* g, void* l) {
  // 16B direct global->LDS. LDS dest is wave-uniform base + lane*16.
  __builtin_amdgcn_global_load_lds(
      (__attribute__((address_space(1))) unsigned int*)g,
      (__attribute__((address_space(3))) unsigned int*)l, 16, 0, 0);
}

// ---------------- fp32 -> bf16 elementwise (4 elems/thread) ----------------
__global__ __launch_bounds__(256) void k_cvt(const float* __restrict__ in,
                                             bf16* __restrict__ out) {
  int i = blockIdx.x * 256 + threadIdx.x;
  float4 v = reinterpret_cast<const float4*>(in)[i];
  bf16x4 o;
  o[0] = (bf16)v.x; o[1] = (bf16)v.y; o[2] = (bf16)v.z; o[3] = (bf16)v.w;
  reinterpret_cast<bf16x4*>(out)[i] = o;
}

// -------- weight transpose+convert: in[K][N] fp32 -> out[N][K] bf16 --------
__global__ __launch_bounds__(256) void k_wT(const float* __restrict__ in,
                                            bf16* __restrict__ out, int K, int N) {
  int t = blockIdx.x * 256 + threadIdx.x;   // over N*K, write-coalesced
  int n = t / K, k = t - n * K;
  out[t] = (bf16)in[(size_t)k * N + n];
}

// ---- V transpose: V[b][m][h*64+d] -> VT[((b*8+h)*64+d)][m]  (bf16) --------
__global__ __launch_bounds__(256) void k_vT(const bf16* __restrict__ V,
                                            bf16* __restrict__ VT) {
  int t = blockIdx.x * 256 + threadIdx.x;   // over B*H*DH*M, write-coalesced
  int m = t & (M_ - 1);
  int rest = t >> 11;          // (b*8+h)*64 + d
  int d = rest & 63;
  int bh = rest >> 6;          // b*8+h
  VT[t] = V[((size_t)((bh >> 3) * M_ + m)) * INNER_ + (bh & 7) * DH_ + d];
}

// ---------------------------------------------------------------------------
// GEMM  C[M x N] = A[M x K] @ BT[N x K]^T   (bf16 in, fp32 acc)
// 128x128 tile, BK=32, 4 waves (each 64x64 = 4x4 frags of 16x16x32 MFMA).
// ---------------------------------------------------------------------------
__device__ __forceinline__ void gemm_core(
    const bf16* __restrict__ A, const bf16* __restrict__ BT,
    bf16* __restrict__ Cb, float* __restrict__ Cf, const float* __restrict__ bias,
    int Kdim, int Ndim, float alpha) {
  __shared__ char lds[16384];          // A: [0,8192)  B: [8192,16384)
  const int t = threadIdx.x;
  const int wid = t >> 6, l = t & 63, g = l >> 4, r16 = l & 15;
  const int wr = wid >> 1, wc = wid & 1;
  const int m0 = blockIdx.x * 128, n0 = blockIdx.y * 128;

  f32x4 acc[4][4];
#pragma unroll
  for (int ai = 0; ai < 4; ++ai)
#pragma unroll
    for (int bj = 0; bj < 4; ++bj) acc[ai][bj] = (f32x4){0.f, 0.f, 0.f, 0.f};

  const int rS = t >> 2;                        // row within issue (0..63)
  const int lsS = (t & 3) ^ ((rS >> 1) & 3);    // logical slot (involution)
  const size_t a0 = (size_t)(m0 + rS) * Kdim + lsS * 8;
  const size_t a1 = (size_t)(m0 + 64 + rS) * Kdim + lsS * 8;
  const size_t b0 = (size_t)(n0 + rS) * Kdim + lsS * 8;
  const size_t b1 = (size_t)(n0 + 64 + rS) * Kdim + lsS * 8;
  char* ldsA = lds;
  char* ldsB = lds + 8192;

  for (int k0 = 0; k0 < Kdim; k0 += 32) {
    __syncthreads();                    // prev compute done before overwrite
    gload_lds16(A + a0 + k0, ldsA + wid * 1024);
    gload_lds16(A + a1 + k0, ldsA + 4096 + wid * 1024);
    gload_lds16(BT + b0 + k0, ldsB + wid * 1024);
    gload_lds16(BT + b1 + k0, ldsB + 4096 + wid * 1024);
    __syncthreads();                    // drains vmcnt before reads

    bf16x8 af[4], bfr[4];
#pragma unroll
    for (int i = 0; i < 4; ++i) {
      const int rowA = wr * 64 + i * 16 + r16;
      af[i] = *reinterpret_cast<const bf16x8*>(
          ldsA + rowA * 64 + ((g ^ ((rowA >> 1) & 3)) << 4));
      const int rowB = wc * 64 + i * 16 + r16;
      bfr[i] = *reinterpret_cast<const bf16x8*>(
          ldsB + rowB * 64 + ((g ^ ((rowB >> 1) & 3)) << 4));
    }
#pragma unroll
    for (int ai = 0; ai < 4; ++ai)
#pragma unroll
      for (int bj = 0; bj < 4; ++bj)
        acc[ai][bj] = __builtin_amdgcn_mfma_f32_16x16x32_bf16(
            af[ai], bfr[bj], acc[ai][bj], 0, 0, 0);
  }

  // epilogue: C/D layout col = lane&15, row = (lane>>4)*4 + reg  [m89]
#pragma unroll
  for (int ai = 0; ai < 4; ++ai)
#pragma unroll
    for (int bj = 0; bj < 4; ++bj)
#pragma unroll
      for (int r = 0; r < 4; ++r) {
        const int row = m0 + wr * 64 + ai * 16 + g * 4 + r;
        const int col = n0 + wc * 64 + bj * 16 + r16;
        const float v = acc[ai][bj][r] * alpha;
        if (Cf) Cf[(size_t)row * Ndim + col] = v + bias[col];
        else    Cb[(size_t)row * Ndim + col] = (bf16)v;
      }
}

// fused QKV projection: z=0 -> Q (K=1024, alpha=1/8), z=1 -> K, z=2 -> V
__global__ __launch_bounds__(256) void k_gemm_qkv(
    const bf16* __restrict__ xb, const bf16* __restrict__ cb,
    const bf16* __restrict__ WqT, const bf16* __restrict__ WkT,
    const bf16* __restrict__ WvT,
    bf16* __restrict__ Q, bf16* __restrict__ K, bf16* __restrict__ V) {
  const int z = blockIdx.z;
  gemm_core(z == 0 ? xb : cb,
            z == 0 ? WqT : (z == 1 ? WkT : WvT),
            z == 0 ? Q : (z == 1 ? K : V),
            nullptr, nullptr,
            z == 0 ? QD_ : CD_, INNER_,
            z == 0 ? 0.125f : 1.0f);
}

__global__ __launch_bounds__(256) void k_gemm_out(
    const bf16* __restrict__ AO, const bf16* __restrict__ WoT,
    float* __restrict__ Cout, const float* __restrict__ bias) {
  gemm_core(AO, WoT, nullptr, Cout, bias, INNER_, QD_, 1.0f);
}

// ---------------------------------------------------------------------------
// Flash attention v2: swapped-QK^T, 32x32x16 MFMA, in-register softmax.
// Block = 4 waves x 32 q-rows = 128 q-rows, one (b,h).  KVBLK = 64.
// LDS: double-buffered K[64][64] + VT[64][64] bf16 tiles (128B rows, 8 x 16B
// slots, XOR slot swizzle by row&7).  K rows staged PERMUTED (bit2<->bit3 of
// row index) so that the swapped-QK^T output lands A-fragment-aligned for PV:
//   S' reg r, half h5 holds P[q=lane&31][kj = (r&3)+4((r>>2)&1)+8*h5
//                                             +16((r>>3)&1)+32*tile]
// => PV A-frag c (kj 16c..16c+15) = regs s[c>>1][8*(c&1) + 0..7] verbatim.
// Online softmax per-lane (1 q-row/lane) + 2 shfl_xor(32); defer-max THR=8.
// ---------------------------------------------------------------------------
__global__ __launch_bounds__(256) void k_attn(const bf16* __restrict__ Qg,
                                              const bf16* __restrict__ Kg,
                                              const bf16* __restrict__ VTg,
                                              bf16* __restrict__ AO) {
  __shared__ char lds[33280];  // buf0 K/VT @0/8192, buf1 @16384/24576, linv @32768
  const int t = threadIdx.x;
  const int w = t >> 6, l = t & 63;
  const int ql = l & 31, h5 = l >> 5;
  const int h = blockIdx.y, b = blockIdx.z;
  const int q0 = blockIdx.x * 128 + w * 32;

  // ---- Q B-frags (held in registers; scale 1/8 folded in by QKV GEMM) ----
  const bf16* qbase =
      Qg + ((size_t)(b * N_ + q0 + ql)) * INNER_ + h * DH_ + 8 * h5;
  bf16x8 qf[4];
#pragma unroll
  for (int j = 0; j < 4; ++j)
    qf[j] = *reinterpret_cast<const bf16x8*>(qbase + 16 * j);

  f32x16 o0, o1;
#pragma unroll
  for (int i = 0; i < 16; ++i) { o0[i] = 0.f; o1[i] = 0.f; }
  float m_run = -1e30f, l_run = 0.f;

  // ---- staging addressing ----
  const int rstg = t >> 3;                    // 0..31 (row within 4KB issue)
  const int ls = (t & 7) ^ (rstg & 7);        // logical slot (involution)
  const int prow = (rstg & ~12) | ((rstg & 4) << 1) | ((rstg & 8) >> 1);
  const size_t kbase = (size_t)(b * M_) * INNER_ + h * DH_;
  const size_t vbase = (size_t)((b * H_ + h) * DH_) * (size_t)M_;

#define STAGE(bi, mm)                                                          \
  {                                                                            \
    char* Kd = lds + (bi)*16384;                                               \
    char* Vd = Kd + 8192;                                                      \
    gload_lds16(Kg + kbase + (size_t)((mm) + prow) * INNER_ + ls * 8,          \
                Kd + w * 1024);                                                \
    gload_lds16(Kg + kbase + (size_t)((mm) + 32 + prow) * INNER_ + ls * 8,     \
                Kd + 4096 + w * 1024);                                         \
    gload_lds16(VTg + vbase + (size_t)rstg * M_ + (mm) + ls * 8,               \
                Vd + w * 1024);                                                \
    gload_lds16(VTg + vbase + (size_t)(32 + rstg) * M_ + (mm) + ls * 8,        \
                Vd + 4096 + w * 1024);                                         \
  }

  STAGE(0, 0)
  __syncthreads();

  for (int mt = 0; mt < M_ / 64; ++mt) {
    const int cur = mt & 1;
    if (mt + 1 < M_ / 64) STAGE(cur ^ 1, (mt + 1) * 64)
    const char* Kl = lds + cur * 16384;
    const char* Vl = Kl + 8192;

    // ---- S' = K_perm x Q  (2 output tiles of 32 kj x 32 q) ----
    f32x16 s0, s1;
#pragma unroll
    for (int i = 0; i < 16; ++i) { s0[i] = 0.f; s1[i] = 0.f; }
#pragma unroll
    for (int j = 0; j < 4; ++j) {
      const int sw = ((2 * j + h5) ^ (ql & 7)) << 4;
      const bf16x8 ka0 = *reinterpret_cast<const bf16x8*>(Kl + ql * 128 + sw);
      s0 = __builtin_amdgcn_mfma_f32_32x32x16_bf16(ka0, qf[j], s0, 0, 0, 0);
      const bf16x8 ka1 =
          *reinterpret_cast<const bf16x8*>(Kl + (ql + 32) * 128 + sw);
      s1 = __builtin_amdgcn_mfma_f32_32x32x16_bf16(ka1, qf[j], s1, 0, 0, 0);
    }

    // ---- online softmax, one q-row per lane (pair with lane^32) ----
    float mx = s0[0];
#pragma unroll
    for (int i = 1; i < 16; ++i) mx = fmaxf(mx, s0[i]);
#pragma unroll
    for (int i = 0; i < 16; ++i) mx = fmaxf(mx, s1[i]);
    mx = fmaxf(mx, __shfl_xor(mx, 32, 64));
    if (!__all(mx <= m_run + 8.0f)) {     // defer-max (T13)
      const float mnew = fmaxf(m_run, mx);
      const float corr = __expf(m_run - mnew);
#pragma unroll
      for (int i = 0; i < 16; ++i) { o0[i] *= corr; o1[i] *= corr; }
      l_run *= corr;
      m_run = mnew;
    }
    float rs = 0.f;
#pragma unroll
    for (int i = 0; i < 16; ++i) { s0[i] = __expf(s0[i] - m_run); rs += s0[i]; }
#pragma unroll
    for (int i = 0; i < 16; ++i) { s1[i] = __expf(s1[i] - m_run); rs += s1[i]; }
    rs += __shfl_xor(rs, 32, 64);
    l_run += rs;

    // ---- P -> bf16 A-frags (layout-aligned thanks to K-row permutation) ----
    bf16x8 pa[4];
#pragma unroll
    for (int c = 0; c < 4; ++c)
#pragma unroll
      for (int j2 = 0; j2 < 8; ++j2)
        pa[c][j2] = (bf16)((c >> 1) ? s1[8 * (c & 1) + j2]
                                    : s0[8 * (c & 1) + j2]);

    // ---- O += P V  (B-frags from VT tile) ----
#pragma unroll
    for (int c = 0; c < 4; ++c) {
      const int sw = ((2 * c + h5) ^ (ql & 7)) << 4;
      const bf16x8 vb0 = *reinterpret_cast<const bf16x8*>(Vl + ql * 128 + sw);
      o0 = __builtin_amdgcn_mfma_f32_32x32x16_bf16(pa[c], vb0, o0, 0, 0, 0);
      const bf16x8 vb1 =
          *reinterpret_cast<const bf16x8*>(Vl + (ql + 32) * 128 + sw);
      o1 = __builtin_amdgcn_mfma_f32_32x32x16_bf16(pa[c], vb1, o1, 0, 0, 0);
    }
    __syncthreads();   // all reads of buf[cur] done; stages into buf^1 landed
  }
#undef STAGE

  // ---- normalize (redistribute 1/l_run via per-wave LDS) + store ----
  float* linv = reinterpret_cast<float*>(lds + 32768) + w * 32;
  if (h5 == 0) linv[ql] = 1.0f / l_run;
  __syncthreads();
#pragma unroll
  for (int r = 0; r < 16; ++r) {
    const int qrow = (r & 3) + 8 * (r >> 2) + 4 * h5;
    const float inv = linv[qrow];
    const size_t base = ((size_t)(b * N_ + q0 + qrow)) * INNER_ + h * DH_;
    AO[base + ql] = (bf16)(o0[r] * inv);
    AO[base + 32 + ql] = (bf16)(o1[r] * inv);
  }
}

// ---------------------------------------------------------------------------
extern "C" void kernel_launch(void* const* d_in, const int* in_sizes, int n_in,
                              void* d_out, int out_size, void* d_ws, size_t ws_size,
                              hipStream_t stream) {
  const float* x   = (const float*)d_in[0];
  const float* ctx = (const float*)d_in[1];
  const float* Wq  = (const float*)d_in[2];
  const float* Wk  = (const float*)d_in[3];
  const float* Wv  = (const float*)d_in[4];
  const float* Wo  = (const float*)d_in[5];
  const float* bo  = (const float*)d_in[6];
  float* out = (float*)d_out;

  char* ws = (char*)d_ws;
  bf16* xb  = (bf16*)ws; ws += (size_t)B_ * N_ * QD_ * 2;
  bf16* cb  = (bf16*)ws; ws += (size_t)B_ * M_ * CD_ * 2;
  bf16* WqT = (bf16*)ws; ws += (size_t)QD_ * INNER_ * 2;
  bf16* WkT = (bf16*)ws; ws += (size_t)CD_ * INNER_ * 2;
  bf16* WvT = (bf16*)ws; ws += (size_t)CD_ * INNER_ * 2;
  bf16* WoT = (bf16*)ws; ws += (size_t)INNER_ * QD_ * 2;
  bf16* Qb  = (bf16*)ws; ws += (size_t)B_ * N_ * INNER_ * 2;
  bf16* Kb  = (bf16*)ws; ws += (size_t)B_ * M_ * INNER_ * 2;
  bf16* Vb  = (bf16*)ws; ws += (size_t)B_ * M_ * INNER_ * 2;
  bf16* VTb = (bf16*)ws; ws += (size_t)B_ * M_ * INNER_ * 2;
  bf16* AOb = (bf16*)ws; ws += (size_t)B_ * N_ * INNER_ * 2;

  k_cvt<<<(B_ * N_ * QD_) / 1024, 256, 0, stream>>>(x, xb);
  k_cvt<<<(B_ * M_ * CD_) / 1024, 256, 0, stream>>>(ctx, cb);
  k_wT<<<(QD_ * INNER_) / 256, 256, 0, stream>>>(Wq, WqT, QD_, INNER_);
  k_wT<<<(CD_ * INNER_) / 256, 256, 0, stream>>>(Wk, WkT, CD_, INNER_);
  k_wT<<<(CD_ * INNER_) / 256, 256, 0, stream>>>(Wv, WvT, CD_, INNER_);
  k_wT<<<(INNER_ * QD_) / 256, 256, 0, stream>>>(Wo, WoT, INNER_, QD_);

  k_gemm_qkv<<<dim3(64, 4, 3), 256, 0, stream>>>(xb, cb, WqT, WkT, WvT,
                                                 Qb, Kb, Vb);
  k_vT<<<(B_ * H_ * DH_ * M_) / 256, 256, 0, stream>>>(Vb, VTb);
  k_attn<<<dim3(N_ / 128, H_, B_), 256, 0, stream>>>(Qb, Kb, VTb, AOb);
  k_gemm_out<<<dim3(64, 8), 256, 0, stream>>>(AOb, WoT, out, bo);
}

// Round 6
// 248.269 us; speedup vs baseline: 1.2261x; 1.0122x over previous
//
#include <hip/hip_runtime.h>
#include <cstdint>
#include <cstddef>

// ---------------------------------------------------------------------------
// CrossAttention: out = softmax((x Wq)(ctx Wk)^T / sqrt(64)) (ctx Wv) Wo + bo
// B=4, N=M=2048, QD=1024, CD=768, H=8, DH=64, INNER=512
// bf16 MFMA pipeline, fp32 accumulation. Softmax in log2 domain (log2e folded
// into the Q projection scale).
// ---------------------------------------------------------------------------

typedef __bf16 bf16;
typedef __bf16 bf16x8 __attribute__((ext_vector_type(8)));
typedef __bf16 bf16x4 __attribute__((ext_vector_type(4)));
typedef float  f32x4  __attribute__((ext_vector_type(4)));
typedef float  f32x16 __attribute__((ext_vector_type(16)));

#define B_     4
#define N_     2048
#define M_     2048
#define QD_    1024
#define CD_    768
#define H_     8
#define DH_    64
#define INNER_ 512

__device__ __forceinline__ void gload_lds16(const void* g, void* l) {
  __builtin_amdgcn_global_load_lds(
      (__attribute__((address_space(1))) unsigned int*)g,
      (__attribute__((address_space(3))) unsigned int*)l, 16, 0, 0);
}

// 2^x via v_exp_f32 (native transcendental; HIP has no __exp2f device fn)
__device__ __forceinline__ float exp2_fast(float x) {
  float r;
  asm("v_exp_f32 %0, %1" : "=v"(r) : "v"(x));
  return r;
}

// ---------------- fp32 -> bf16 elementwise (4 elems/thread) ----------------
__global__ __launch_bounds__(256) void k_cvt(const float* __restrict__ in,
                                             bf16* __restrict__ out) {
  int i = blockIdx.x * 256 + threadIdx.x;
  float4 v = reinterpret_cast<const float4*>(in)[i];
  bf16x4 o;
  o[0] = (bf16)v.x; o[1] = (bf16)v.y; o[2] = (bf16)v.z; o[3] = (bf16)v.w;
  reinterpret_cast<bf16x4*>(out)[i] = o;
}

// -------- weight transpose+convert: in[K][N] fp32 -> out[N][K] bf16 --------
__global__ __launch_bounds__(256) void k_wT(const float* __restrict__ in,
                                            bf16* __restrict__ out, int K, int N) {
  int t = blockIdx.x * 256 + threadIdx.x;   // over N*K, write-coalesced
  int n = t / K, k = t - n * K;
  out[t] = (bf16)in[(size_t)k * N + n];
}

// ---------------------------------------------------------------------------
// GEMM  C[M x N] = A[M x K] @ BT[N x K]^T   (bf16 in, fp32 acc)
// 128x128 tile, BK=32, 4 waves, double-buffered LDS (prefetch-before-compute,
// one barrier per K-step).  LDS tiles [128 rows][32 cols] bf16, XOR-swizzled
// slots (involution applied to global src of global_load_lds and ds_read).
// Epilogue modes: Cb (bf16 row-major), Cf (+bias, fp32), Cvt (bf16 scatter
// into VT[(b*8+h)*64+d][m] layout -- used by the V projection).
// ---------------------------------------------------------------------------
__device__ __forceinline__ void gemm_core(
    const bf16* __restrict__ A, const bf16* __restrict__ BT,
    bf16* __restrict__ Cb, bf16* __restrict__ Cvt, float* __restrict__ Cf,
    const float* __restrict__ bias, int Kdim, int Ndim, float alpha) {
  __shared__ char lds[32768];          // 2 bufs x (A 8KB + B 8KB)
  const int t = threadIdx.x;
  const int wid = t >> 6, l = t & 63, g = l >> 4, r16 = l & 15;
  const int wr = wid >> 1, wc = wid & 1;
  const int m0 = blockIdx.x * 128, n0 = blockIdx.y * 128;

  f32x4 acc[4][4];
#pragma unroll
  for (int ai = 0; ai < 4; ++ai)
#pragma unroll
    for (int bj = 0; bj < 4; ++bj) acc[ai][bj] = (f32x4){0.f, 0.f, 0.f, 0.f};

  const int rS = t >> 2;                        // row within issue (0..63)
  const int lsS = (t & 3) ^ ((rS >> 1) & 3);    // logical slot (involution)
  const size_t a0 = (size_t)(m0 + rS) * Kdim + lsS * 8;
  const size_t a1 = (size_t)(m0 + 64 + rS) * Kdim + lsS * 8;
  const size_t b0 = (size_t)(n0 + rS) * Kdim + lsS * 8;
  const size_t b1 = (size_t)(n0 + 64 + rS) * Kdim + lsS * 8;

#define GSTAGE(bi, kk)                                                         \
  {                                                                            \
    char* ldsA = lds + (bi)*16384;                                             \
    char* ldsB = ldsA + 8192;                                                  \
    gload_lds16(A + a0 + (kk), ldsA + wid * 1024);                             \
    gload_lds16(A + a1 + (kk), ldsA + 4096 + wid * 1024);                      \
    gload_lds16(BT + b0 + (kk), ldsB + wid * 1024);                            \
    gload_lds16(BT + b1 + (kk), ldsB + 4096 + wid * 1024);                     \
  }

  GSTAGE(0, 0)
  __syncthreads();

  const int nk = Kdim >> 5;
  for (int kt = 0; kt < nk; ++kt) {
    const int cur = kt & 1;
    if (kt + 1 < nk) GSTAGE(cur ^ 1, (kt + 1) * 32)
    const char* ldsA = lds + cur * 16384;
    const char* ldsB = ldsA + 8192;

    bf16x8 af[4], bfr[4];
#pragma unroll
    for (int i = 0; i < 4; ++i) {
      const int rowA = wr * 64 + i * 16 + r16;
      af[i] = *reinterpret_cast<const bf16x8*>(
          ldsA + rowA * 64 + ((g ^ ((rowA >> 1) & 3)) << 4));
      const int rowB = wc * 64 + i * 16 + r16;
      bfr[i] = *reinterpret_cast<const bf16x8*>(
          ldsB + rowB * 64 + ((g ^ ((rowB >> 1) & 3)) << 4));
    }
#pragma unroll
    for (int ai = 0; ai < 4; ++ai)
#pragma unroll
      for (int bj = 0; bj < 4; ++bj)
        acc[ai][bj] = __builtin_amdgcn_mfma_f32_16x16x32_bf16(
            af[ai], bfr[bj], acc[ai][bj], 0, 0, 0);
    __syncthreads();
  }
#undef GSTAGE

  // epilogue: C/D layout col = lane&15, row = (lane>>4)*4 + reg  [m89]
#pragma unroll
  for (int ai = 0; ai < 4; ++ai)
#pragma unroll
    for (int bj = 0; bj < 4; ++bj)
#pragma unroll
      for (int r = 0; r < 4; ++r) {
        const int row = m0 + wr * 64 + ai * 16 + g * 4 + r;
        const int col = n0 + wc * 64 + bj * 16 + r16;
        const float v = acc[ai][bj][r] * alpha;
        if (Cf) {
          Cf[(size_t)row * Ndim + col] = v + bias[col];
        } else if (Cvt) {
          // V scatter: row=(b,m), col=(h,d) -> VT[((b*8+h)*64+d)][m]
          const size_t vt =
              (((size_t)(row >> 11) * 8 + (col >> 6)) * 64 + (col & 63)) * M_ +
              (row & (M_ - 1));
          Cvt[vt] = (bf16)v;
        } else {
          Cb[(size_t)row * Ndim + col] = (bf16)v;
        }
      }
}

// fused QKV projection: z=0 -> Q (K=1024, alpha=log2e/8), z=1 -> K, z=2 -> VT
__global__ __launch_bounds__(256) void k_gemm_qkv(
    const bf16* __restrict__ xb, const bf16* __restrict__ cb,
    const bf16* __restrict__ WqT, const bf16* __restrict__ WkT,
    const bf16* __restrict__ WvT,
    bf16* __restrict__ Q, bf16* __restrict__ K, bf16* __restrict__ VT) {
  const int z = blockIdx.z;
  gemm_core(z == 0 ? xb : cb,
            z == 0 ? WqT : (z == 1 ? WkT : WvT),
            z == 0 ? Q : K,
            z == 2 ? VT : nullptr,
            nullptr, nullptr,
            z == 0 ? QD_ : CD_, INNER_,
            z == 0 ? 0.18033688f /* log2e/8 */ : 1.0f);
}

__global__ __launch_bounds__(256) void k_gemm_out(
    const bf16* __restrict__ AO, const bf16* __restrict__ WoT,
    float* __restrict__ Cout, const float* __restrict__ bias) {
  gemm_core(AO, WoT, nullptr, nullptr, Cout, bias, INNER_, QD_, 1.0f);
}

// ---------------------------------------------------------------------------
// Flash attention v3: swapped-QK^T, 32x32x16 MFMA, in-register softmax in
// log2 domain.  Block = 2 waves x 32 q-rows = 64 q-rows, one (b,h).
// KVBLK = 64; double-buffered K[64][64] + VT[64][64] tiles (128B rows,
// 8x16B slots, XOR slot swizzle by row&7).  K rows staged bit2<->bit3
// permuted so S' lands A-fragment-aligned for PV.  Softmax denominator via
// ones-B-frag MFMA (l in same C-layout as O).  Wave-uniform running max
// (exactly-correct uniform rescale) + defer-max THR=11.5 bits.
// ---------------------------------------------------------------------------
__global__ __launch_bounds__(128) void k_attn(const bf16* __restrict__ Qg,
                                              const bf16* __restrict__ Kg,
                                              const bf16* __restrict__ VTg,
                                              bf16* __restrict__ AO) {
  __shared__ char lds[32768];  // buf0 K/VT @0/8192, buf1 @16384/24576
  const int t = threadIdx.x;
  const int w = t >> 6, l = t & 63;
  const int ql = l & 31, h5 = l >> 5;
  const int h = blockIdx.y, b = blockIdx.z;
  const int q0 = blockIdx.x * 64 + w * 32;

  // ---- Q B-frags (scale log2e/8 folded in by the QKV GEMM) ----
  const bf16* qbase =
      Qg + ((size_t)(b * N_ + q0 + ql)) * INNER_ + h * DH_ + 8 * h5;
  bf16x8 qf[4];
#pragma unroll
  for (int j = 0; j < 4; ++j)
    qf[j] = *reinterpret_cast<const bf16x8*>(qbase + 16 * j);

  bf16x8 onesf;
#pragma unroll
  for (int j = 0; j < 8; ++j) onesf[j] = (bf16)1.0f;

  f32x16 o0, o1, lA;
#pragma unroll
  for (int i = 0; i < 16; ++i) { o0[i] = 0.f; o1[i] = 0.f; lA[i] = 0.f; }
  float m_run = -1e30f;

  // ---- staging addressing (128 thr: 4 rounds of 16 rows per 8KB tile) ----
  const int rstg = t >> 3;                    // 0..15
  const int ls = (t & 7) ^ (rstg & 7);        // logical slot (involution)
  const int perm = (rstg & 3) | ((rstg & 4) << 1) | ((rstg & 8) >> 1);
  const size_t kbase = (size_t)(b * M_) * INNER_ + h * DH_;
  const size_t vbase = (size_t)((b * H_ + h) * DH_) * (size_t)M_;

#define STAGE(bi, mm)                                                          \
  {                                                                            \
    char* Kd = lds + (bi)*16384;                                               \
    char* Vd = Kd + 8192;                                                      \
    _Pragma("unroll") for (int rr = 0; rr < 4; ++rr) {                         \
      gload_lds16(Kg + kbase + (size_t)((mm) + rr * 16 + perm) * INNER_ +      \
                      ls * 8,                                                  \
                  Kd + rr * 2048 + w * 1024);                                  \
      gload_lds16(VTg + vbase + (size_t)(rr * 16 + rstg) * M_ + (mm) + ls * 8, \
                  Vd + rr * 2048 + w * 1024);                                  \
    }                                                                          \
  }

  STAGE(0, 0)
  __syncthreads();

  for (int mt = 0; mt < M_ / 64; ++mt) {
    const int cur = mt & 1;
    if (mt + 1 < M_ / 64) STAGE(cur ^ 1, (mt + 1) * 64)
    const char* Kl = lds + cur * 16384;
    const char* Vl = Kl + 8192;

    // ---- S' = K_perm x Q ----
    f32x16 s0, s1;
#pragma unroll
    for (int i = 0; i < 16; ++i) { s0[i] = 0.f; s1[i] = 0.f; }
    __builtin_amdgcn_s_setprio(1);
#pragma unroll
    for (int j = 0; j < 4; ++j) {
      const int sw = ((2 * j + h5) ^ (ql & 7)) << 4;
      const bf16x8 ka0 = *reinterpret_cast<const bf16x8*>(Kl + ql * 128 + sw);
      s0 = __builtin_amdgcn_mfma_f32_32x32x16_bf16(ka0, qf[j], s0, 0, 0, 0);
      const bf16x8 ka1 =
          *reinterpret_cast<const bf16x8*>(Kl + (ql + 32) * 128 + sw);
      s1 = __builtin_amdgcn_mfma_f32_32x32x16_bf16(ka1, qf[j], s1, 0, 0, 0);
    }
    __builtin_amdgcn_s_setprio(0);

    // ---- wave-uniform running max (log2 units) + defer-max rescale ----
    float mx = fmaxf(fmaxf(s0[0], s0[1]), fmaxf(s0[2], s0[3]));
#pragma unroll
    for (int i = 4; i < 16; i += 3)
      mx = fmaxf(fmaxf(mx, s0[i]), fmaxf(s0[i + 1], s0[i + 2]));
#pragma unroll
    for (int i = 0; i < 16; i += 4)
      mx = fmaxf(fmaxf(mx, s1[i]),
                 fmaxf(fmaxf(s1[i + 1], s1[i + 2]), s1[i + 3]));
#pragma unroll
    for (int off = 1; off <= 32; off <<= 1)
      mx = fmaxf(mx, __shfl_xor(mx, off, 64));
    if (mx > m_run + 11.5f) {            // wave-uniform branch
      const float corr = exp2_fast(m_run - mx);
#pragma unroll
      for (int i = 0; i < 16; ++i) {
        o0[i] *= corr; o1[i] *= corr; lA[i] *= corr;
      }
      m_run = mx;
    }
#pragma unroll
    for (int i = 0; i < 16; ++i) s0[i] = exp2_fast(s0[i] - m_run);
#pragma unroll
    for (int i = 0; i < 16; ++i) s1[i] = exp2_fast(s1[i] - m_run);

    // ---- O += P V ; l += P 1  (P A-frags register-aligned) ----
    __builtin_amdgcn_s_setprio(1);
#pragma unroll
    for (int c = 0; c < 4; ++c) {
      bf16x8 pa;
#pragma unroll
      for (int j2 = 0; j2 < 8; ++j2)
        pa[j2] = (bf16)((c >= 2) ? s1[8 * (c & 1) + j2] : s0[8 * (c & 1) + j2]);
      const int sw = ((2 * c + h5) ^ (ql & 7)) << 4;
      const bf16x8 vb0 = *reinterpret_cast<const bf16x8*>(Vl + ql * 128 + sw);
      o0 = __builtin_amdgcn_mfma_f32_32x32x16_bf16(pa, vb0, o0, 0, 0, 0);
      const bf16x8 vb1 =
          *reinterpret_cast<const bf16x8*>(Vl + (ql + 32) * 128 + sw);
      o1 = __builtin_amdgcn_mfma_f32_32x32x16_bf16(pa, vb1, o1, 0, 0, 0);
      lA = __builtin_amdgcn_mfma_f32_32x32x16_bf16(pa, onesf, lA, 0, 0, 0);
    }
    __builtin_amdgcn_s_setprio(0);
    __syncthreads();   // reads of buf[cur] done; stages into buf^1 landed
  }
#undef STAGE

  // ---- normalize + store (l already in o's C-layout; no cross-lane) ----
#pragma unroll
  for (int r = 0; r < 16; ++r) {
    const float inv = __builtin_amdgcn_rcpf(lA[r]);
    const int qrow = (r & 3) + 8 * (r >> 2) + 4 * h5;
    const size_t base = ((size_t)(b * N_ + q0 + qrow)) * INNER_ + h * DH_;
    AO[base + ql] = (bf16)(o0[r] * inv);
    AO[base + 32 + ql] = (bf16)(o1[r] * inv);
  }
}

// ---------------------------------------------------------------------------
extern "C" void kernel_launch(void* const* d_in, const int* in_sizes, int n_in,
                              void* d_out, int out_size, void* d_ws, size_t ws_size,
                              hipStream_t stream) {
  const float* x   = (const float*)d_in[0];
  const float* ctx = (const float*)d_in[1];
  const float* Wq  = (const float*)d_in[2];
  const float* Wk  = (const float*)d_in[3];
  const float* Wv  = (const float*)d_in[4];
  const float* Wo  = (const float*)d_in[5];
  const float* bo  = (const float*)d_in[6];
  float* out = (float*)d_out;

  char* ws = (char*)d_ws;
  bf16* xb  = (bf16*)ws; ws += (size_t)B_ * N_ * QD_ * 2;
  bf16* cb  = (bf16*)ws; ws += (size_t)B_ * M_ * CD_ * 2;
  bf16* WqT = (bf16*)ws; ws += (size_t)QD_ * INNER_ * 2;
  bf16* WkT = (bf16*)ws; ws += (size_t)CD_ * INNER_ * 2;
  bf16* WvT = (bf16*)ws; ws += (size_t)CD_ * INNER_ * 2;
  bf16* WoT = (bf16*)ws; ws += (size_t)INNER_ * QD_ * 2;
  bf16* Qb  = (bf16*)ws; ws += (size_t)B_ * N_ * INNER_ * 2;
  bf16* Kb  = (bf16*)ws; ws += (size_t)B_ * M_ * INNER_ * 2;
  bf16* VTb = (bf16*)ws; ws += (size_t)B_ * M_ * INNER_ * 2;
  bf16* AOb = (bf16*)ws; ws += (size_t)B_ * N_ * INNER_ * 2;

  k_cvt<<<(B_ * N_ * QD_) / 1024, 256, 0, stream>>>(x, xb);
  k_cvt<<<(B_ * M_ * CD_) / 1024, 256, 0, stream>>>(ctx, cb);
  k_wT<<<(QD_ * INNER_) / 256, 256, 0, stream>>>(Wq, WqT, QD_, INNER_);
  k_wT<<<(CD_ * INNER_) / 256, 256, 0, stream>>>(Wk, WkT, CD_, INNER_);
  k_wT<<<(CD_ * INNER_) / 256, 256, 0, stream>>>(Wv, WvT, CD_, INNER_);
  k_wT<<<(INNER_ * QD_) / 256, 256, 0, stream>>>(Wo, WoT, INNER_, QD_);

  k_gemm_qkv<<<dim3(64, 4, 3), 256, 0, stream>>>(xb, cb, WqT, WkT, WvT,
                                                 Qb, Kb, VTb);
  k_attn<<<dim3(N_ / 64, H_, B_), 128, 0, stream>>>(Qb, Kb, VTb, AOb);
  k_gemm_out<<<dim3(64, 8), 256, 0, stream>>>(AOb, WoT, out, bo);
}

// Round 11
// 231.792 us; speedup vs baseline: 1.3133x; 1.0711x over previous
//
#include <hip/hip_runtime.h>
#include <cstdint>
#include <cstddef>

// ---------------------------------------------------------------------------
// CrossAttention: out = softmax((x Wq)(ctx Wk)^T / sqrt(64)) (ctx Wv) Wo + bo
// B=4, N=M=2048, QD=1024, CD=768, H=8, DH=64, INNER=512
// bf16 MFMA pipeline, fp32 accumulation. Softmax in log2 domain (log2e folded
// into the Q projection scale).
// ---------------------------------------------------------------------------

typedef __bf16 bf16;
typedef __bf16 bf16x8 __attribute__((ext_vector_type(8)));
typedef __bf16 bf16x4 __attribute__((ext_vector_type(4)));
typedef float  f32x4  __attribute__((ext_vector_type(4)));
typedef float  f32x16 __attribute__((ext_vector_type(16)));

#define B_     4
#define N_     2048
#define M_     2048
#define QD_    1024
#define CD_    768
#define H_     8
#define DH_    64
#define INNER_ 512

__device__ __forceinline__ void gload_lds16(const void* g, void* l) {
  __builtin_amdgcn_global_load_lds(
      (__attribute__((address_space(1))) unsigned int*)g,
      (__attribute__((address_space(3))) unsigned int*)l, 16, 0, 0);
}

// 2^x via v_exp_f32 (native transcendental; HIP has no __exp2f device fn)
__device__ __forceinline__ float exp2_fast(float x) {
  float r;
  asm("v_exp_f32 %0, %1" : "=v"(r) : "v"(x));
  return r;
}

// ------- fused fp32 -> bf16 conversion for x and ctx (4 elems/thread) ------
#define NX4_ ((size_t)B_ * N_ * QD_ / 4)     // 2097152 float4s of x
#define NC4_ ((size_t)B_ * M_ * CD_ / 4)     // 1572864 float4s of ctx
__global__ __launch_bounds__(256) void k_cvt2(const float* __restrict__ x,
                                              const float* __restrict__ ctx,
                                              bf16* __restrict__ xb,
                                              bf16* __restrict__ cb) {
  size_t i = (size_t)blockIdx.x * 256 + threadIdx.x;
  const float* in;
  bf16* out;
  size_t j;
  if (i < NX4_) { in = x; out = xb; j = i; }
  else          { in = ctx; out = cb; j = i - NX4_; }
  float4 v = reinterpret_cast<const float4*>(in)[j];
  bf16x4 o;
  o[0] = (bf16)v.x; o[1] = (bf16)v.y; o[2] = (bf16)v.z; o[3] = (bf16)v.w;
  reinterpret_cast<bf16x4*>(out)[j] = o;
}

// -- fused weight transpose+convert via LDS tile: in[K][N] f32 -> out[N][K] --
// z selects {Wq, Wk, Wv, Wo}; grid covers max dims, block-uniform guard.
__global__ __launch_bounds__(256) void k_wT4(
    const float* __restrict__ Wq, const float* __restrict__ Wk,
    const float* __restrict__ Wv, const float* __restrict__ Wo,
    bf16* __restrict__ WqT, bf16* __restrict__ WkT,
    bf16* __restrict__ WvT, bf16* __restrict__ WoT) {
  const int z = blockIdx.z;
  const float* in = z == 0 ? Wq : (z == 1 ? Wk : (z == 2 ? Wv : Wo));
  bf16* out = z == 0 ? WqT : (z == 1 ? WkT : (z == 2 ? WvT : WoT));
  const int K = z == 0 ? QD_ : (z == 3 ? INNER_ : CD_);
  const int N = z == 3 ? QD_ : INNER_;
  const int k0 = blockIdx.x * 32, n0 = blockIdx.y * 32;
  if (k0 >= K || n0 >= N) return;
  __shared__ float tile[32][33];               // +1 pad: conflict-free cols
  const int tx = threadIdx.x & 31, ty = threadIdx.x >> 5;  // 8 rows/pass
#pragma unroll
  for (int i = 0; i < 32; i += 8)
    tile[ty + i][tx] = in[(size_t)(k0 + ty + i) * N + n0 + tx];
  __syncthreads();
#pragma unroll
  for (int i = 0; i < 32; i += 8)
    out[(size_t)(n0 + ty + i) * K + k0 + tx] = (bf16)tile[tx][ty + i];
}

// ---------------------------------------------------------------------------
// GEMM  C[M x N] = A[M x K] @ BT[N x K]^T   (bf16 in, fp32 acc)
// 128x128 tile, BK=32, 4 waves, double-buffered LDS (prefetch-before-compute,
// one barrier per K-step).  XOR-swizzled slots (involution applied to global
// src of global_load_lds and to the ds_read address).
// ---------------------------------------------------------------------------
__device__ __forceinline__ void gemm_core(
    const bf16* __restrict__ A, const bf16* __restrict__ BT,
    bf16* __restrict__ Cb, bf16* __restrict__ Cvt, float* __restrict__ Cf,
    const float* __restrict__ bias, int Kdim, int Ndim, float alpha) {
  __shared__ char lds[32768];          // 2 bufs x (A 8KB + B 8KB)
  const int t = threadIdx.x;
  const int wid = t >> 6, l = t & 63, g = l >> 4, r16 = l & 15;
  const int wr = wid >> 1, wc = wid & 1;
  const int m0 = blockIdx.x * 128, n0 = blockIdx.y * 128;

  f32x4 acc[4][4];
#pragma unroll
  for (int ai = 0; ai < 4; ++ai)
#pragma unroll
    for (int bj = 0; bj < 4; ++bj) acc[ai][bj] = (f32x4){0.f, 0.f, 0.f, 0.f};

  const int rS = t >> 2;                        // row within issue (0..63)
  const int lsS = (t & 3) ^ ((rS >> 1) & 3);    // logical slot (involution)
  const size_t a0 = (size_t)(m0 + rS) * Kdim + lsS * 8;
  const size_t a1 = (size_t)(m0 + 64 + rS) * Kdim + lsS * 8;
  const size_t b0 = (size_t)(n0 + rS) * Kdim + lsS * 8;
  const size_t b1 = (size_t)(n0 + 64 + rS) * Kdim + lsS * 8;

#define GSTAGE(bi, kk)                                                         \
  {                                                                            \
    char* ldsA = lds + (bi)*16384;                                             \
    char* ldsB = ldsA + 8192;                                                  \
    gload_lds16(A + a0 + (kk), ldsA + wid * 1024);                             \
    gload_lds16(A + a1 + (kk), ldsA + 4096 + wid * 1024);                      \
    gload_lds16(BT + b0 + (kk), ldsB + wid * 1024);                            \
    gload_lds16(BT + b1 + (kk), ldsB + 4096 + wid * 1024);                     \
  }

  GSTAGE(0, 0)
  __syncthreads();

  const int nk = Kdim >> 5;
  for (int kt = 0; kt < nk; ++kt) {
    const int cur = kt & 1;
    if (kt + 1 < nk) GSTAGE(cur ^ 1, (kt + 1) * 32)
    const char* ldsA = lds + cur * 16384;
    const char* ldsB = ldsA + 8192;

    bf16x8 af[4], bfr[4];
#pragma unroll
    for (int i = 0; i < 4; ++i) {
      const int rowA = wr * 64 + i * 16 + r16;
      af[i] = *reinterpret_cast<const bf16x8*>(
          ldsA + rowA * 64 + ((g ^ ((rowA >> 1) & 3)) << 4));
      const int rowB = wc * 64 + i * 16 + r16;
      bfr[i] = *reinterpret_cast<const bf16x8*>(
          ldsB + rowB * 64 + ((g ^ ((rowB >> 1) & 3)) << 4));
    }
#pragma unroll
    for (int ai = 0; ai < 4; ++ai)
#pragma unroll
      for (int bj = 0; bj < 4; ++bj)
        acc[ai][bj] = __builtin_amdgcn_mfma_f32_16x16x32_bf16(
            af[ai], bfr[bj], acc[ai][bj], 0, 0, 0);
    __syncthreads();
  }
#undef GSTAGE

  // epilogue: C/D layout col = lane&15, row = (lane>>4)*4 + reg  [m89]
#pragma unroll
  for (int ai = 0; ai < 4; ++ai)
#pragma unroll
    for (int bj = 0; bj < 4; ++bj)
#pragma unroll
      for (int r = 0; r < 4; ++r) {
        const int row = m0 + wr * 64 + ai * 16 + g * 4 + r;
        const int col = n0 + wc * 64 + bj * 16 + r16;
        const float v = acc[ai][bj][r] * alpha;
        if (Cf) {
          Cf[(size_t)row * Ndim + col] = v + bias[col];
        } else if (Cvt) {
          // V scatter: row=(b,m), col=(h,d) -> VT[((b*8+h)*64+d)][m]
          const size_t vt =
              (((size_t)(row >> 11) * 8 + (col >> 6)) * 64 + (col & 63)) * M_ +
              (row & (M_ - 1));
          Cvt[vt] = (bf16)v;
        } else {
          Cb[(size_t)row * Ndim + col] = (bf16)v;
        }
      }
}

// fused QKV projection: z=0 -> Q (K=1024, alpha=log2e/8), z=1 -> K, z=2 -> VT
__global__ __launch_bounds__(256) void k_gemm_qkv(
    const bf16* __restrict__ xb, const bf16* __restrict__ cb,
    const bf16* __restrict__ WqT, const bf16* __restrict__ WkT,
    const bf16* __restrict__ WvT,
    bf16* __restrict__ Q, bf16* __restrict__ K, bf16* __restrict__ VT) {
  const int z = blockIdx.z;
  gemm_core(z == 0 ? xb : cb,
            z == 0 ? WqT : (z == 1 ? WkT : WvT),
            z == 0 ? Q : K,
            z == 2 ? VT : nullptr,
            nullptr, nullptr,
            z == 0 ? QD_ : CD_, INNER_,
            z == 0 ? 0.18033688f /* log2e/8 */ : 1.0f);
}

__global__ __launch_bounds__(256) void k_gemm_out(
    const bf16* __restrict__ AO, const bf16* __restrict__ WoT,
    float* __restrict__ Cout, const float* __restrict__ bias) {
  gemm_core(AO, WoT, nullptr, nullptr, Cout, bias, INNER_, QD_, 1.0f);
}

// ---------------------------------------------------------------------------
// Flash attention v3 (byte-identical to the Round-6 PASSING version):
// swapped-QK^T, 32x32x16 MFMA, in-register softmax in log2 domain.
// Block = 2 waves x 32 q-rows = 64 q-rows, one (b,h).  KVBLK = 64,
// double-buffered K[64][64] + VT[64][64] tiles.  K rows staged bit2<->bit3
// permuted so S' lands A-frag-aligned for PV.  Denominator via ones-B-frag
// MFMA.  Wave-uniform running max + defer-max THR=11.5 bits.
// ---------------------------------------------------------------------------
__global__ __launch_bounds__(128) void k_attn(const bf16* __restrict__ Qg,
                                              const bf16* __restrict__ Kg,
                                              const bf16* __restrict__ VTg,
                                              bf16* __restrict__ AO) {
  __shared__ char lds[32768];  // buf0 K/VT @0/8192, buf1 @16384/24576
  const int t = threadIdx.x;
  const int w = t >> 6, l = t & 63;
  const int ql = l & 31, h5 = l >> 5;
  const int h = blockIdx.y, b = blockIdx.z;
  const int q0 = blockIdx.x * 64 + w * 32;

  // ---- Q B-frags (scale log2e/8 folded in by the QKV GEMM) ----
  const bf16* qbase =
      Qg + ((size_t)(b * N_ + q0 + ql)) * INNER_ + h * DH_ + 8 * h5;
  bf16x8 qf[4];
#pragma unroll
  for (int j = 0; j < 4; ++j)
    qf[j] = *reinterpret_cast<const bf16x8*>(qbase + 16 * j);

  bf16x8 onesf;
#pragma unroll
  for (int j = 0; j < 8; ++j) onesf[j] = (bf16)1.0f;

  f32x16 o0, o1, lA;
#pragma unroll
  for (int i = 0; i < 16; ++i) { o0[i] = 0.f; o1[i] = 0.f; lA[i] = 0.f; }
  float m_run = -1e30f;

  // ---- staging addressing (128 thr: 4 rounds of 16 rows per 8KB tile) ----
  const int rstg = t >> 3;                    // 0..15
  const int ls = (t & 7) ^ (rstg & 7);        // logical slot (involution)
  const int perm = (rstg & 3) | ((rstg & 4) << 1) | ((rstg & 8) >> 1);
  const size_t kbase = (size_t)(b * M_) * INNER_ + h * DH_;
  const size_t vbase = (size_t)((b * H_ + h) * DH_) * (size_t)M_;

#define STAGE(bi, mm)                                                          \
  {                                                                            \
    char* Kd = lds + (bi)*16384;                                               \
    char* Vd = Kd + 8192;                                                      \
    _Pragma("unroll") for (int rr = 0; rr < 4; ++rr) {                         \
      gload_lds16(Kg + kbase + (size_t)((mm) + rr * 16 + perm) * INNER_ +      \
                      ls * 8,                                                  \
                  Kd + rr * 2048 + w * 1024);                                  \
      gload_lds16(VTg + vbase + (size_t)(rr * 16 + rstg) * M_ + (mm) + ls * 8, \
                  Vd + rr * 2048 + w * 1024);                                  \
    }                                                                          \
  }

  STAGE(0, 0)
  __syncthreads();

  for (int mt = 0; mt < M_ / 64; ++mt) {
    const int cur = mt & 1;
    if (mt + 1 < M_ / 64) STAGE(cur ^ 1, (mt + 1) * 64)
    const char* Kl = lds + cur * 16384;
    const char* Vl = Kl + 8192;

    // ---- S' = K_perm x Q ----
    f32x16 s0, s1;
#pragma unroll
    for (int i = 0; i < 16; ++i) { s0[i] = 0.f; s1[i] = 0.f; }
    __builtin_amdgcn_s_setprio(1);
#pragma unroll
    for (int j = 0; j < 4; ++j) {
      const int sw = ((2 * j + h5) ^ (ql & 7)) << 4;
      const bf16x8 ka0 = *reinterpret_cast<const bf16x8*>(Kl + ql * 128 + sw);
      s0 = __builtin_amdgcn_mfma_f32_32x32x16_bf16(ka0, qf[j], s0, 0, 0, 0);
      const bf16x8 ka1 =
          *reinterpret_cast<const bf16x8*>(Kl + (ql + 32) * 128 + sw);
      s1 = __builtin_amdgcn_mfma_f32_32x32x16_bf16(ka1, qf[j], s1, 0, 0, 0);
    }
    __builtin_amdgcn_s_setprio(0);

    // ---- wave-uniform running max (log2 units) + defer-max rescale ----
    float mx = fmaxf(fmaxf(s0[0], s0[1]), fmaxf(s0[2], s0[3]));
#pragma unroll
    for (int i = 4; i < 16; i += 3)
      mx = fmaxf(fmaxf(mx, s0[i]), fmaxf(s0[i + 1], s0[i + 2]));
#pragma unroll
    for (int i = 0; i < 16; i += 4)
      mx = fmaxf(fmaxf(mx, s1[i]),
                 fmaxf(fmaxf(s1[i + 1], s1[i + 2]), s1[i + 3]));
#pragma unroll
    for (int off = 1; off <= 32; off <<= 1)
      mx = fmaxf(mx, __shfl_xor(mx, off, 64));
    if (mx > m_run + 11.5f) {            // wave-uniform branch
      const float corr = exp2_fast(m_run - mx);
#pragma unroll
      for (int i = 0; i < 16; ++i) {
        o0[i] *= corr; o1[i] *= corr; lA[i] *= corr;
      }
      m_run = mx;
    }
#pragma unroll
    for (int i = 0; i < 16; ++i) s0[i] = exp2_fast(s0[i] - m_run);
#pragma unroll
    for (int i = 0; i < 16; ++i) s1[i] = exp2_fast(s1[i] - m_run);

    // ---- O += P V ; l += P 1  (P A-frags register-aligned) ----
    __builtin_amdgcn_s_setprio(1);
#pragma unroll
    for (int c = 0; c < 4; ++c) {
      bf16x8 pa;
#pragma unroll
      for (int j2 = 0; j2 < 8; ++j2)
        pa[j2] = (bf16)((c >= 2) ? s1[8 * (c & 1) + j2] : s0[8 * (c & 1) + j2]);
      const int sw = ((2 * c + h5) ^ (ql & 7)) << 4;
      const bf16x8 vb0 = *reinterpret_cast<const bf16x8*>(Vl + ql * 128 + sw);
      o0 = __builtin_amdgcn_mfma_f32_32x32x16_bf16(pa, vb0, o0, 0, 0, 0);
      const bf16x8 vb1 =
          *reinterpret_cast<const bf16x8*>(Vl + (ql + 32) * 128 + sw);
      o1 = __builtin_amdgcn_mfma_f32_32x32x16_bf16(pa, vb1, o1, 0, 0, 0);
      lA = __builtin_amdgcn_mfma_f32_32x32x16_bf16(pa, onesf, lA, 0, 0, 0);
    }
    __builtin_amdgcn_s_setprio(0);
    __syncthreads();   // reads of buf[cur] done; stages into buf^1 landed
  }
#undef STAGE

  // ---- normalize + store (l already in o's C-layout; no cross-lane) ----
#pragma unroll
  for (int r = 0; r < 16; ++r) {
    const float inv = __builtin_amdgcn_rcpf(lA[r]);
    const int qrow = (r & 3) + 8 * (r >> 2) + 4 * h5;
    const size_t base = ((size_t)(b * N_ + q0 + qrow)) * INNER_ + h * DH_;
    AO[base + ql] = (bf16)(o0[r] * inv);
    AO[base + 32 + ql] = (bf16)(o1[r] * inv);
  }
}

// ---------------------------------------------------------------------------
extern "C" void kernel_launch(void* const* d_in, const int* in_sizes, int n_in,
                              void* d_out, int out_size, void* d_ws, size_t ws_size,
                              hipStream_t stream) {
  const float* x   = (const float*)d_in[0];
  const float* ctx = (const float*)d_in[1];
  const float* Wq  = (const float*)d_in[2];
  const float* Wk  = (const float*)d_in[3];
  const float* Wv  = (const float*)d_in[4];
  const float* Wo  = (const float*)d_in[5];
  const float* bo  = (const float*)d_in[6];
  float* out = (float*)d_out;

  char* ws = (char*)d_ws;
  bf16* xb  = (bf16*)ws; ws += (size_t)B_ * N_ * QD_ * 2;
  bf16* cb  = (bf16*)ws; ws += (size_t)B_ * M_ * CD_ * 2;
  bf16* WqT = (bf16*)ws; ws += (size_t)QD_ * INNER_ * 2;
  bf16* WkT = (bf16*)ws; ws += (size_t)CD_ * INNER_ * 2;
  bf16* WvT = (bf16*)ws; ws += (size_t)CD_ * INNER_ * 2;
  bf16* WoT = (bf16*)ws; ws += (size_t)INNER_ * QD_ * 2;
  bf16* Qb  = (bf16*)ws; ws += (size_t)B_ * N_ * INNER_ * 2;
  bf16* Kb  = (bf16*)ws; ws += (size_t)B_ * M_ * INNER_ * 2;
  bf16* VTb = (bf16*)ws; ws += (size_t)B_ * M_ * INNER_ * 2;
  bf16* AOb = (bf16*)ws; ws += (size_t)B_ * N_ * INNER_ * 2;

  k_cvt2<<<(unsigned)((NX4_ + NC4_) / 256), 256, 0, stream>>>(x, ctx, xb, cb);
  k_wT4<<<dim3(32, 32, 4), 256, 0, stream>>>(Wq, Wk, Wv, Wo,
                                             WqT, WkT, WvT, WoT);

  k_gemm_qkv<<<dim3(64, 4, 3), 256, 0, stream>>>(xb, cb, WqT, WkT, WvT,
                                                 Qb, Kb, VTb);
  k_attn<<<dim3(N_ / 64, H_, B_), 128, 0, stream>>>(Qb, Kb, VTb, AOb);
  k_gemm_out<<<dim3(64, 8), 256, 0, stream>>>(AOb, WoT, out, bo);
}